// Round 1
// 116.566 us; speedup vs baseline: 1.0238x; 1.0238x over previous
//
#include <hip/hip_runtime.h>

// Live computation only (GNN layers are dead code in the reference):
//   hg[b] = [mean(h_comp|g==b), mean2(h_port|g==b), mean(h_net|g==b)]  -> [64,4]
//   out = relu(relu(hg@Wc1+bc1)@Wc2+bc2)@Wc3+bc3                        -> [64,10]
//
// R6 structure: ONE kernel, 64 blocks (one per graph), NO workspace.
// gid_* are sorted (reference does jnp.sort), so each graph's nodes are a
// contiguous range. Each block:
//   1. wave-parallel 64-ary lower_bound finds [lo,hi) for its graph in each
//      gid array (~4 dependent global probes; waves 0/1/2 handle comp/port/net)
//   2. float4-vectorized sums over the contiguous feature slices
//      (counts are hi-lo, free — no counting pass, no gid streaming)
//   3. block reduce + the tiny 3-layer MLP
// This removes: the second launch, the inter-kernel drain, 1 MB of ws
// round-trip traffic, all LDS-atomic binning, and 2.6 MB of gid reads.

#define NGRAPH 64
#define BLK 512

// Wave-cooperative lower_bound over sorted int array a[0..n).
// All 64 lanes of one wave must call together. ~4 rounds for n=400000.
__device__ __forceinline__ int wave_lb(const int* __restrict__ a, int n, int key) {
    int lane = threadIdx.x & 63;
    int lo = 0;
    int len = n;  // invariant: lower_bound in [lo, lo+len]
    while (len > 0) {
        int chunk = (len + 63) >> 6;       // >= 1
        int off = lane * chunk;
        bool valid = off < len;
        int v = valid ? a[lo + off] : 0;
        unsigned long long m = __ballot(valid && (v < key));
        int c = __popcll(m);               // probes form a sorted prefix
        if (c == 0) {
            len = 0;                       // a[lo] >= key -> answer is lo
        } else {
            int nlo = lo + (c - 1) * chunk + 1;   // a[nlo-1] < key
            int hi = lo + min(c * chunk, len);    // a[hi] >= key (or end)
            lo = nlo;
            len = hi - nlo;
        }
    }
    return lo;
}

__global__ __launch_bounds__(BLK) void fused_kernel(
    const float* __restrict__ h_comp, const float* __restrict__ h_port,
    const float* __restrict__ h_net,
    const int* __restrict__ gid_comp, const int* __restrict__ gid_port,
    const int* __restrict__ gid_net,
    int n_comp, int n_port, int n_net,
    const float* __restrict__ Wc1, const float* __restrict__ bc1,
    const float* __restrict__ Wc2, const float* __restrict__ bc2,
    const float* __restrict__ Wc3, const float* __restrict__ bc3,
    float* __restrict__ out) {
    __shared__ int rng[6];
    __shared__ float wred[BLK / 64][4];
    __shared__ float hgs[4];
    __shared__ float h1[128];
    __shared__ float part[4][128];
    __shared__ float h2[128];
    __shared__ float l3[16][12];  // 10 used, pad

    const int g = blockIdx.x;
    const int tid = threadIdx.x;
    const int wave = tid >> 6;

    // ---- Phase 1: range search (waves 0..2, each: lb(g) then lb(g+1)) ----
    if (wave == 0) {
        int lo = wave_lb(gid_comp, n_comp, g);
        int hi = wave_lb(gid_comp, n_comp, g + 1);
        if ((tid & 63) == 0) { rng[0] = lo; rng[1] = hi; }
    } else if (wave == 1) {
        int lo = wave_lb(gid_port, n_port, g);
        int hi = wave_lb(gid_port, n_port, g + 1);
        if ((tid & 63) == 0) { rng[2] = lo; rng[3] = hi; }
    } else if (wave == 2) {
        int lo = wave_lb(gid_net, n_net, g);
        int hi = wave_lb(gid_net, n_net, g + 1);
        if ((tid & 63) == 0) { rng[4] = lo; rng[5] = hi; }
    }
    __syncthreads();

    const int c0 = rng[0], c1 = rng[1];
    const int p0 = rng[2], p1 = rng[3];
    const int q0 = rng[4], q1 = rng[5];

    // ---- Phase 2: contiguous-range sums (float4 body, scalar edges) ----
    float sc = 0.f, s0 = 0.f, s1 = 0.f, sn = 0.f;

    {  // comp: 1 feature
        int a4 = min(c1, (c0 + 3) & ~3);
        for (int i = c0 + tid; i < a4; i += BLK) sc += h_comp[i];
        int nv = (c1 - a4) >> 2;
        const float4* hv = (const float4*)(h_comp + a4);
        for (int iv = tid; iv < nv; iv += BLK) {
            float4 v = hv[iv];
            sc += (v.x + v.y) + (v.z + v.w);
        }
        for (int i = a4 + nv * 4 + tid; i < c1; i += BLK) sc += h_comp[i];
    }
    {  // port: 2 features interleaved; float4 = 2 nodes
        int a2 = min(p1, (p0 + 1) & ~1);
        for (int i = p0 + tid; i < a2; i += BLK) { s0 += h_port[2 * i]; s1 += h_port[2 * i + 1]; }
        int nv = (p1 - a2) >> 1;
        const float4* hv = (const float4*)(h_port + 2 * a2);
        for (int iv = tid; iv < nv; iv += BLK) {
            float4 v = hv[iv];
            s0 += v.x + v.z;
            s1 += v.y + v.w;
        }
        for (int i = a2 + nv * 2 + tid; i < p1; i += BLK) { s0 += h_port[2 * i]; s1 += h_port[2 * i + 1]; }
    }
    {  // net: 1 feature
        int a4 = min(q1, (q0 + 3) & ~3);
        for (int i = q0 + tid; i < a4; i += BLK) sn += h_net[i];
        int nv = (q1 - a4) >> 2;
        const float4* hv = (const float4*)(h_net + a4);
        for (int iv = tid; iv < nv; iv += BLK) {
            float4 v = hv[iv];
            sn += (v.x + v.y) + (v.z + v.w);
        }
        for (int i = a4 + nv * 4 + tid; i < q1; i += BLK) sn += h_net[i];
    }

    // ---- Block reduce 4 partials; counts are free (range widths) ----
#pragma unroll
    for (int off = 32; off > 0; off >>= 1) {
        sc += __shfl_down(sc, off);
        s0 += __shfl_down(s0, off);
        s1 += __shfl_down(s1, off);
        sn += __shfl_down(sn, off);
    }
    if ((tid & 63) == 0) {
        wred[wave][0] = sc; wred[wave][1] = s0;
        wred[wave][2] = s1; wred[wave][3] = sn;
    }
    __syncthreads();
    if (tid == 0) {
        float a = 0.f, b = 0.f, c = 0.f, d = 0.f;
#pragma unroll
        for (int w = 0; w < BLK / 64; ++w) {
            a += wred[w][0]; b += wred[w][1]; c += wred[w][2]; d += wred[w][3];
        }
        hgs[0] = a / fmaxf((float)(c1 - c0), 1.f);
        hgs[1] = b / fmaxf((float)(p1 - p0), 1.f);
        hgs[2] = c / fmaxf((float)(p1 - p0), 1.f);
        hgs[3] = d / fmaxf((float)(q1 - q0), 1.f);
    }
    __syncthreads();

    // ---- Layer 1: [4] @ [4,128] ----
    if (tid < 128) {
        float v = hgs[0] * Wc1[tid] + hgs[1] * Wc1[128 + tid] +
                  hgs[2] * Wc1[256 + tid] + hgs[3] * Wc1[384 + tid] + bc1[tid];
        h1[tid] = fmaxf(v, 0.f);
    }
    __syncthreads();

    // ---- Layer 2: [128] @ [128,128], split-k over 4 quarter-ranges ----
    {
        int j = tid & 127;
        int hq = tid >> 7;  // 0..3
        float acc = 0.f;
#pragma unroll
        for (int kk = 0; kk < 32; kk += 4) {
            int k = hq * 32 + kk;
            float4 hh = *(const float4*)&h1[k];
            acc += hh.x * Wc2[(k + 0) * 128 + j] + hh.y * Wc2[(k + 1) * 128 + j] +
                   hh.z * Wc2[(k + 2) * 128 + j] + hh.w * Wc2[(k + 3) * 128 + j];
        }
        part[hq][j] = acc;
    }
    __syncthreads();
    if (tid < 128)
        h2[tid] = fmaxf(part[0][tid] + part[1][tid] + part[2][tid] + part[3][tid] + bc2[tid], 0.f);
    __syncthreads();

    // ---- Layer 3: [128] @ [128,10], split-k over 16 segments of 8 ----
    if (tid < 160) {
        int c = tid % 10;
        int seg = tid / 10;
        float a = 0.f;
#pragma unroll
        for (int k = seg * 8; k < seg * 8 + 8; ++k) a += h2[k] * Wc3[k * 10 + c];
        l3[seg][c] = a;
    }
    __syncthreads();
    if (tid < 10) {
        float a = bc3[tid];
#pragma unroll
        for (int s = 0; s < 16; ++s) a += l3[s][tid];
        out[g * 10 + tid] = a;
    }
}

extern "C" void kernel_launch(void* const* d_in, const int* in_sizes, int n_in,
                              void* d_out, int out_size, void* d_ws, size_t ws_size,
                              hipStream_t stream) {
    const float* h_comp = (const float*)d_in[0];
    const float* h_port = (const float*)d_in[1];
    const float* h_net  = (const float*)d_in[2];
    // d_in[3..6]: edge arrays — dead code in the reference, unused.
    const int* gid_comp = (const int*)d_in[7];
    const int* gid_port = (const int*)d_in[8];
    const int* gid_net  = (const int*)d_in[9];
    // d_in[10..21]: GraphConv weights — dead code, unused.
    const float* Wc1 = (const float*)d_in[22];
    const float* bc1 = (const float*)d_in[23];
    const float* Wc2 = (const float*)d_in[24];
    const float* bc2 = (const float*)d_in[25];
    const float* Wc3 = (const float*)d_in[26];
    const float* bc3 = (const float*)d_in[27];

    int n_comp = in_sizes[0];      // 100000 (dim 1)
    int n_port = in_sizes[1] / 2;  // 400000 (dim 2)
    int n_net  = in_sizes[2];      // 150000 (dim 1)

    float* out = (float*)d_out;
    (void)d_ws; (void)ws_size;  // no workspace needed

    fused_kernel<<<NGRAPH, BLK, 0, stream>>>(
        h_comp, h_port, h_net, gid_comp, gid_port, gid_net,
        n_comp, n_port, n_net,
        Wc1, bc1, Wc2, bc2, Wc3, bc3, out);
}